// Round 1
// baseline (1875.093 us; speedup 1.0000x reference)
//
#include <hip/hip_runtime.h>

#define NR 768
#define CZ 128
#define NNF (768*768)   // 589824

typedef __bf16 bf16;
typedef __bf16 bf16x8 __attribute__((ext_vector_type(8)));
typedef __bf16 bf16x4 __attribute__((ext_vector_type(4)));
typedef float  f32x4  __attribute__((ext_vector_type(4)));

__device__ __forceinline__ void cp16(void* lds, const void* g) {
    __builtin_amdgcn_global_load_lds(
        (const __attribute__((address_space(1))) void*)g,
        (__attribute__((address_space(3))) void*)lds, 16, 0, 0);
}

__device__ __forceinline__ float sigmoidf_(float x) {
    return 1.f / (1.f + __expf(-x));
}

// ---------------------------------------------------------------------------
// Kernel 1: LN(act) -> xhat(bf16); 5 projections via MFMA; emit
//   leftT[c][i][k], rightT[c][j][k] (bf16, channel-major) and gate[p][c] (bf16)
// Block: 64 rows of the flattened [NN x 128] activation; 256 threads.
// ---------------------------------------------------------------------------
__global__ __launch_bounds__(256, 2)
void k1_ln_proj(const float* __restrict__ act,  const float* __restrict__ mask,
                const float* __restrict__ lnw,  const float* __restrict__ lnb,
                const float* __restrict__ W0,   const float* __restrict__ W1,
                const float* __restrict__ W2,   const float* __restrict__ W3,
                const float* __restrict__ W4,
                const float* __restrict__ b0,   const float* __restrict__ b1,
                const float* __restrict__ b2,   const float* __restrict__ b3,
                const float* __restrict__ b4,
                bf16* __restrict__ leftT, bf16* __restrict__ rightT,
                bf16* __restrict__ gate)
{
    __shared__ bf16 sXh[64*136];     // xhat [row][k], stride 136 (16B-aligned rows, padded)
    __shared__ bf16 sWt[128*136];    // W transposed [n][k]
    __shared__ bf16 sStage[128*68];  // staging: [c][m] stride 68  OR  [m][c] stride 132
    __shared__ float sSum[64], sSsq[64], sMask[64];

    const int tid = threadIdx.x;
    const int r0  = blockIdx.x * 64;
    const int g32 = tid >> 5;        // 0..7
    const int l32 = tid & 31;
    const int col = l32 * 4;

    // Phase A: load 64x128 act into regs, per-row stats via 32-lane shuffles
    float4 v[8];
#pragma unroll
    for (int it = 0; it < 8; ++it) {
        int row = it*8 + g32;
        v[it] = *(const float4*)(act + (size_t)(r0+row)*CZ + col);
        float s = v[it].x + v[it].y + v[it].z + v[it].w;
        float q = v[it].x*v[it].x + v[it].y*v[it].y + v[it].z*v[it].z + v[it].w*v[it].w;
#pragma unroll
        for (int off = 16; off > 0; off >>= 1) {
            s += __shfl_down(s, off, 32);
            q += __shfl_down(q, off, 32);
        }
        if (l32 == 0) { sSum[row] = s; sSsq[row] = q; }
    }
    if (tid < 64) sMask[tid] = mask[r0 + tid];
    __syncthreads();

    // write xhat (bf16) to LDS
    {
        float4 w4 = *(const float4*)(lnw + col);
        float4 b4 = *(const float4*)(lnb + col);
#pragma unroll
        for (int it = 0; it < 8; ++it) {
            int row = it*8 + g32;
            float mu  = sSum[row] * (1.f/CZ);
            float var = sSsq[row] * (1.f/CZ) - mu*mu;
            float rs  = rsqrtf(var + 1e-5f);
            bf16x4 o;
            o[0] = (bf16)((v[it].x - mu)*rs*w4.x + b4.x);
            o[1] = (bf16)((v[it].y - mu)*rs*w4.y + b4.y);
            o[2] = (bf16)((v[it].z - mu)*rs*w4.z + b4.z);
            o[3] = (bf16)((v[it].w - mu)*rs*w4.w + b4.w);
            *(bf16x4*)(sXh + row*136 + col) = o;
        }
    }

    const float* Ws[5] = {W0, W1, W2, W3, W4};
    const float* bs[5] = {b0, b1, b2, b3, b4};
    const int wv = tid >> 6, lane = tid & 63, l16 = lane & 15, quad = lane >> 4;

    f32x4 accP[8];
    for (int wi = 0; wi < 5; ++wi) {
        __syncthreads();   // guards sWt overwrite and sStage reuse
        const float* W = Ws[wi];
#pragma unroll
        for (int i = 0; i < 16; ++i) {            // W [k][n] fp32 -> sWt[n][k] bf16
            int chunk = tid + i*256;
            int kk = chunk >> 5;
            int nb = (chunk & 31) * 4;
            float4 w = *(const float4*)(W + kk*CZ + nb);
            sWt[(nb+0)*136 + kk] = (bf16)w.x;
            sWt[(nb+1)*136 + kk] = (bf16)w.y;
            sWt[(nb+2)*136 + kk] = (bf16)w.z;
            sWt[(nb+3)*136 + kk] = (bf16)w.w;
        }
        __syncthreads();

        f32x4 acc[8];
        f32x4 zero = {0.f, 0.f, 0.f, 0.f};
#pragma unroll
        for (int t = 0; t < 8; ++t) acc[t] = zero;
#pragma unroll
        for (int ks = 0; ks < 4; ++ks) {
            bf16x8 af = *(const bf16x8*)(sXh + (wv*16 + l16)*136 + ks*32 + quad*8);
#pragma unroll
            for (int t = 0; t < 8; ++t) {
                bf16x8 bfr = *(const bf16x8*)(sWt + (t*16 + l16)*136 + ks*32 + quad*8);
                acc[t] = __builtin_amdgcn_mfma_f32_16x16x32_bf16(af, bfr, acc[t], 0, 0, 0);
            }
        }

        if (wi == 0 || wi == 2) {
#pragma unroll
            for (int t = 0; t < 8; ++t) accP[t] = acc[t];
        } else if (wi == 1 || wi == 3) {
            // combine p-branch with gate-branch -> left/right, stage as [c][m]
            bf16* dst = (wi == 1) ? leftT : rightT;
#pragma unroll
            for (int t = 0; t < 8; ++t) {
                int c = t*16 + l16;
                float bp = bs[wi-1][c];
                float bg = bs[wi][c];
#pragma unroll
                for (int r = 0; r < 4; ++r) {
                    int m = wv*16 + quad*4 + r;
                    float val = sMask[m] * (accP[t][r] + bp) * sigmoidf_(acc[t][r] + bg);
                    sStage[c*68 + m] = (bf16)val;
                }
            }
            __syncthreads();
#pragma unroll
            for (int i = 0; i < 8; ++i) {          // 128 c-rows x 16 ushort4 chunks
                int chunk = tid + i*256;
                int c = chunk >> 4, u = chunk & 15;
                *(bf16x4*)(dst + (size_t)c*NNF + r0 + u*4) =
                    *(const bf16x4*)(sStage + c*68 + u*4);
            }
        } else {
            // gate = sigmoid(x@Wg + bg), stage as [m][c] then coalesced write
#pragma unroll
            for (int t = 0; t < 8; ++t) {
                int c = t*16 + l16;
                float bg = bs[4][c];
#pragma unroll
                for (int r = 0; r < 4; ++r) {
                    int m = wv*16 + quad*4 + r;
                    sStage[m*132 + c] = (bf16)sigmoidf_(acc[t][r] + bg);
                }
            }
            __syncthreads();
#pragma unroll
            for (int i = 0; i < 8; ++i) {
                int chunk = tid + i*256;
                int m = chunk >> 5, c4 = chunk & 31;
                *(bf16x4*)(gate + (size_t)(r0+m)*CZ + c4*4) =
                    *(const bf16x4*)(sStage + m*132 + c4*4);
            }
        }
    }
}

// ---------------------------------------------------------------------------
// Kernel 2: per-channel GEMM  Mid[c][i][j] = sum_k L[c][i][k] * R[c][j][k]
// m97-style: 128x128 tile, BK=32, global_load_lds width 16. Grid (6,6,128).
// ---------------------------------------------------------------------------
__global__ __launch_bounds__(256, 2)
void k2_einsum(const bf16* __restrict__ Lt, const bf16* __restrict__ Rt,
               bf16* __restrict__ Mid)
{
    __shared__ bf16 sA[128*32];
    __shared__ bf16 sB[128*32];

    const int tid = threadIdx.x;
    const int bj = blockIdx.x, bi = blockIdx.y, c = blockIdx.z;
    const size_t cb = (size_t)c * NNF;
    const bf16* Ab = Lt + cb + (size_t)bi * 128 * NR;
    const bf16* Bb = Rt + cb + (size_t)bj * 128 * NR;

    const int wv = tid >> 6, lane = tid & 63, l16 = lane & 15, quad = lane >> 4;
    const int m0 = (wv >> 1) * 64, n0 = (wv & 1) * 64;

    // staging chunk mapping: chunk q -> row q/4, k-offset (q&3)*8 ; LDS = q*16B
    const int q0 = tid, q1 = tid + 256;
    const int ra0 = q0 >> 2, kc0 = (q0 & 3) * 8;
    const int ra1 = q1 >> 2, kc1 = (q1 & 3) * 8;
    bf16* lbA0 = sA + (size_t)(wv*64) * 8;          // wave-uniform LDS bases
    bf16* lbA1 = sA + (size_t)(256 + wv*64) * 8;
    bf16* lbB0 = sB + (size_t)(wv*64) * 8;
    bf16* lbB1 = sB + (size_t)(256 + wv*64) * 8;

    f32x4 acc[4][4];
    f32x4 zero = {0.f, 0.f, 0.f, 0.f};
#pragma unroll
    for (int mi = 0; mi < 4; ++mi)
#pragma unroll
        for (int ni = 0; ni < 4; ++ni) acc[mi][ni] = zero;

    for (int ko = 0; ko < NR; ko += 32) {
        __syncthreads();
        cp16(lbA0, Ab + (size_t)ra0*NR + ko + kc0);
        cp16(lbA1, Ab + (size_t)ra1*NR + ko + kc1);
        cp16(lbB0, Bb + (size_t)ra0*NR + ko + kc0);
        cp16(lbB1, Bb + (size_t)ra1*NR + ko + kc1);
        __syncthreads();

        bf16x8 af[4], bfr[4];
#pragma unroll
        for (int i = 0; i < 4; ++i) {
            af[i]  = *(const bf16x8*)(sA + (m0 + i*16 + l16)*32 + quad*8);
            bfr[i] = *(const bf16x8*)(sB + (n0 + i*16 + l16)*32 + quad*8);
        }
#pragma unroll
        for (int mi = 0; mi < 4; ++mi)
#pragma unroll
            for (int ni = 0; ni < 4; ++ni)
                acc[mi][ni] = __builtin_amdgcn_mfma_f32_16x16x32_bf16(
                                  af[mi], bfr[ni], acc[mi][ni], 0, 0, 0);
    }

    bf16* Ob = Mid + cb + (size_t)(bi*128) * NR + bj*128;
#pragma unroll
    for (int mi = 0; mi < 4; ++mi)
#pragma unroll
        for (int ni = 0; ni < 4; ++ni) {
            int colv = n0 + ni*16 + l16;
#pragma unroll
            for (int r = 0; r < 4; ++r) {
                int row = m0 + mi*16 + quad*4 + r;
                Ob[(size_t)row*NR + colv] = (bf16)acc[mi][ni][r];
            }
        }
}

// ---------------------------------------------------------------------------
// Kernel 3: transpose [C][NN] -> LN over c -> @W_out + b_out -> * gate -> out
// Block: 64 flat positions; 256 threads.
// ---------------------------------------------------------------------------
__global__ __launch_bounds__(256, 2)
void k3_ln_out(const bf16* __restrict__ Mid, const bf16* __restrict__ gate,
               const float* __restrict__ lnw, const float* __restrict__ lnb,
               const float* __restrict__ Wout, const float* __restrict__ bout,
               float* __restrict__ out)
{
    __shared__ bf16 sT[128*68];     // [c][pos]
    __shared__ bf16 sXh[64*136];    // [pos][c]
    __shared__ bf16 sWt[128*136];
    __shared__ float sMu[64], sRs[64];

    const int tid = threadIdx.x;
    const size_t p0 = (size_t)blockIdx.x * 64;

    // Phase A: coalesced load of the 128 x 64 Mid tile (bf16)
#pragma unroll
    for (int i = 0; i < 8; ++i) {
        int chunk = tid + i*256;
        int c = chunk >> 4, u = chunk & 15;
        *(bf16x4*)(sT + c*68 + u*4) =
            *(const bf16x4*)(Mid + (size_t)c*NNF + p0 + u*4);
    }
    // W_out [k][n] fp32 -> sWt[n][k] bf16 (no dependency on sT)
#pragma unroll
    for (int i = 0; i < 16; ++i) {
        int chunk = tid + i*256;
        int kk = chunk >> 5;
        int nb = (chunk & 31) * 4;
        float4 w = *(const float4*)(Wout + kk*CZ + nb);
        sWt[(nb+0)*136 + kk] = (bf16)w.x;
        sWt[(nb+1)*136 + kk] = (bf16)w.y;
        sWt[(nb+2)*136 + kk] = (bf16)w.z;
        sWt[(nb+3)*136 + kk] = (bf16)w.w;
    }
    __syncthreads();

    // Phase B: LN stats over c (4 threads per position)
    {
        int pos = tid >> 2, part = tid & 3;
        float s = 0.f, q = 0.f;
#pragma unroll
        for (int j = 0; j < 32; ++j) {
            float x = (float)sT[(part*32 + j)*68 + pos];
            s += x; q += x*x;
        }
        s += __shfl_xor(s, 1); q += __shfl_xor(q, 1);
        s += __shfl_xor(s, 2); q += __shfl_xor(q, 2);
        if (part == 0) {
            float mu  = s * (1.f/CZ);
            float var = q * (1.f/CZ) - mu*mu;
            sMu[pos] = mu;
            sRs[pos] = rsqrtf(var + 1e-5f);
        }
    }
    __syncthreads();

    // Phase C: xhat[pos][c] (bf16) = LN result
#pragma unroll
    for (int i2 = 0; i2 < 8; ++i2) {
        int id = tid + i2*256;
        int pos = id & 63, c4 = id >> 6;
        float mu = sMu[pos], rs = sRs[pos];
        float4 w = *(const float4*)(lnw + c4*4);
        float4 b = *(const float4*)(lnb + c4*4);
        bf16x4 o;
        o[0] = (bf16)(((float)sT[(c4*4+0)*68 + pos] - mu)*rs*w.x + b.x);
        o[1] = (bf16)(((float)sT[(c4*4+1)*68 + pos] - mu)*rs*w.y + b.y);
        o[2] = (bf16)(((float)sT[(c4*4+2)*68 + pos] - mu)*rs*w.z + b.z);
        o[3] = (bf16)(((float)sT[(c4*4+3)*68 + pos] - mu)*rs*w.w + b.w);
        *(bf16x4*)(sXh + pos*136 + c4*4) = o;
    }
    __syncthreads();

    // Phase D: [64 x 128] @ W_out via MFMA, then bias + gate, store fp32
    const int wv = tid >> 6, lane = tid & 63, l16 = lane & 15, quad = lane >> 4;
    f32x4 acc[8];
    f32x4 zero = {0.f, 0.f, 0.f, 0.f};
#pragma unroll
    for (int t = 0; t < 8; ++t) acc[t] = zero;
#pragma unroll
    for (int ks = 0; ks < 4; ++ks) {
        bf16x8 af = *(const bf16x8*)(sXh + (wv*16 + l16)*136 + ks*32 + quad*8);
#pragma unroll
        for (int t = 0; t < 8; ++t) {
            bf16x8 bfr = *(const bf16x8*)(sWt + (t*16 + l16)*136 + ks*32 + quad*8);
            acc[t] = __builtin_amdgcn_mfma_f32_16x16x32_bf16(af, bfr, acc[t], 0, 0, 0);
        }
    }
#pragma unroll
    for (int t = 0; t < 8; ++t) {
        int c = t*16 + l16;
        float bo = bout[c];
#pragma unroll
        for (int r = 0; r < 4; ++r) {
            int m = wv*16 + quad*4 + r;
            size_t p = p0 + m;
            float g = (float)gate[p*CZ + c];
            out[p*CZ + c] = (acc[t][r] + bo) * g;
        }
    }
}

// ---------------------------------------------------------------------------
extern "C" void kernel_launch(void* const* d_in, const int* in_sizes, int n_in,
                              void* d_out, int out_size, void* d_ws, size_t ws_size,
                              hipStream_t stream)
{
    const float* act     = (const float*)d_in[0];
    const float* mask    = (const float*)d_in[1];
    const float* ln_in_w = (const float*)d_in[2];
    const float* ln_in_b = (const float*)d_in[3];
    const float* W_lp    = (const float*)d_in[4];
    const float* b_lp    = (const float*)d_in[5];
    const float* W_rp    = (const float*)d_in[6];
    const float* b_rp    = (const float*)d_in[7];
    const float* W_lg    = (const float*)d_in[8];
    const float* b_lg    = (const float*)d_in[9];
    const float* W_rg    = (const float*)d_in[10];
    const float* b_rg    = (const float*)d_in[11];
    const float* ln_c_w  = (const float*)d_in[12];
    const float* ln_c_b  = (const float*)d_in[13];
    const float* W_out   = (const float*)d_in[14];
    const float* b_out   = (const float*)d_in[15];
    const float* W_g     = (const float*)d_in[16];
    const float* b_g     = (const float*)d_in[17];

    char* ws = (char*)d_ws;
    const size_t SZ = (size_t)NNF * CZ * sizeof(bf16);   // 150,994,944 B each
    bf16* leftT  = (bf16*)(ws);
    bf16* rightT = (bf16*)(ws + SZ);
    bf16* gatev  = (bf16*)(ws + 2*SZ);
    bf16* Mid    = (bf16*)(ws + 3*SZ);
    (void)ws_size; (void)in_sizes; (void)n_in; (void)out_size;

    k1_ln_proj<<<NNF/64, 256, 0, stream>>>(act, mask, ln_in_w, ln_in_b,
        W_lp, W_lg, W_rp, W_rg, W_g,
        b_lp, b_lg, b_rp, b_rg, b_g,
        leftT, rightT, gatev);

    k2_einsum<<<dim3(6, 6, 128), 256, 0, stream>>>(leftT, rightT, Mid);

    k3_ln_out<<<NNF/64, 256, 0, stream>>>(Mid, gatev, ln_c_w, ln_c_b,
        W_out, b_out, (float*)d_out);
}

// Round 2
// 1531.233 us; speedup vs baseline: 1.2246x; 1.2246x over previous
//
#include <hip/hip_runtime.h>

#define NR 768
#define CZ 128
#define NNF (768*768)   // 589824

typedef __bf16 bf16;
typedef __bf16 bf16x8 __attribute__((ext_vector_type(8)));
typedef __bf16 bf16x4 __attribute__((ext_vector_type(4)));
typedef float  f32x4  __attribute__((ext_vector_type(4)));

__device__ __forceinline__ void cp16(void* lds, const void* g) {
    __builtin_amdgcn_global_load_lds(
        (const __attribute__((address_space(1))) void*)g,
        (__attribute__((address_space(3))) void*)lds, 16, 0, 0);
}

__device__ __forceinline__ float sigmoidf_(float x) {
    return 1.f / (1.f + __expf(-x));
}

// ---------------------------------------------------------------------------
// k0: convert 5 weights [k][n] fp32 -> Wt[w][n][k] bf16 (one-time, tiny)
// ---------------------------------------------------------------------------
__global__ void k0_wt(const float* __restrict__ W0, const float* __restrict__ W1,
                      const float* __restrict__ W2, const float* __restrict__ W3,
                      const float* __restrict__ W4, bf16* __restrict__ Wt)
{
    const float* Ws[5] = {W0, W1, W2, W3, W4};
    const float* W = Ws[blockIdx.x];
    bf16* dst = Wt + blockIdx.x * 16384;
#pragma unroll 4
    for (int i = 0; i < 64; ++i) {
        int idx = i*256 + threadIdx.x;
        int k = idx >> 7, n = idx & 127;
        dst[n*128 + k] = (bf16)W[idx];   // coalesced read, scattered write (tiny)
    }
}

// ---------------------------------------------------------------------------
// k1: per 128-row tile x branch {left,right,gate}: inline LN -> MFMA GEMM
//     against pre-transposed bf16 weights -> fused sigmoid/mask epilogue.
// left/right written channel-major [c][p]; gate row-major [p][c].
// ---------------------------------------------------------------------------
__global__ __launch_bounds__(256, 2)
void k1_proj(const float* __restrict__ act,  const float* __restrict__ mask,
             const float* __restrict__ lnw,  const float* __restrict__ lnb,
             const bf16*  __restrict__ Wt,
             const float* __restrict__ b_lp, const float* __restrict__ b_lg,
             const float* __restrict__ b_rp, const float* __restrict__ b_rg,
             const float* __restrict__ b_g,
             bf16* __restrict__ leftT, bf16* __restrict__ rightT,
             bf16* __restrict__ gate)
{
    __shared__ bf16 sXh[128*136];   // xhat [row][k], stride 136 (16B-aligned rows)
    __shared__ bf16 sB0[128*32];    // W_p chunk [n][32]
    __shared__ bf16 sB1[128*32];    // W_g chunk [n][32]
    __shared__ float sMask[128], sSum[128], sSsq[128];

    const int tid    = threadIdx.x;
    const int branch = blockIdx.x;          // 0=left 1=right 2=gate
    const size_t p0  = (size_t)blockIdx.y * 128;

    // --- Phase A: LN over 128 rows (32 lanes per row, fp32 in regs) ---
    const int l32 = tid & 31, g8 = tid >> 5;
    const int col = l32 * 4;
    float4 v[16];
#pragma unroll
    for (int it = 0; it < 16; ++it) {
        int row = it*8 + g8;
        v[it] = *(const float4*)(act + (p0+row)*CZ + col);
        float s = v[it].x + v[it].y + v[it].z + v[it].w;
        float q = v[it].x*v[it].x + v[it].y*v[it].y + v[it].z*v[it].z + v[it].w*v[it].w;
#pragma unroll
        for (int off = 16; off > 0; off >>= 1) {
            s += __shfl_down(s, off, 32);
            q += __shfl_down(q, off, 32);
        }
        if (l32 == 0) { sSum[row] = s; sSsq[row] = q; }
    }
    if (tid < 128) sMask[tid] = mask[p0 + tid];
    __syncthreads();
    {
        float4 w4 = *(const float4*)(lnw + col);
        float4 b4 = *(const float4*)(lnb + col);
#pragma unroll
        for (int it = 0; it < 16; ++it) {
            int row = it*8 + g8;
            float mu  = sSum[row] * (1.f/CZ);
            float var = sSsq[row] * (1.f/CZ) - mu*mu;
            float rs  = rsqrtf(var + 1e-5f);
            bf16x4 o;
            o[0] = (bf16)((v[it].x - mu)*rs*w4.x + b4.x);
            o[1] = (bf16)((v[it].y - mu)*rs*w4.y + b4.y);
            o[2] = (bf16)((v[it].z - mu)*rs*w4.z + b4.z);
            o[3] = (bf16)((v[it].w - mu)*rs*w4.w + b4.w);
            *(bf16x4*)(sXh + row*136 + col) = o;
        }
    }

    // --- branch weight/bias selection ---
    const bf16 *Bp, *Bg = nullptr;
    const float *bpb, *bgb = nullptr;
    if (branch == 0)      { Bp = Wt;          Bg = Wt + 16384;   bpb = b_lp; bgb = b_lg; }
    else if (branch == 1) { Bp = Wt + 32768;  Bg = Wt + 49152;   bpb = b_rp; bgb = b_rg; }
    else                  { Bp = Wt + 65536;                     bpb = b_g; }

    const int wv = tid >> 6, lane = tid & 63, l16 = lane & 15, quad = lane >> 4;
    const int m0 = (wv >> 1) * 64, n0 = (wv & 1) * 64;

    // B staging chunk mapping: chunk q -> n-row q>>2, k-off (q&3)*8; LDS q*16B
    const int q0 = tid, q1 = tid + 256;
    const int nr0 = q0 >> 2, kc0 = (q0 & 3) * 8;
    const int nr1 = q1 >> 2, kc1 = (q1 & 3) * 8;
    bf16* lb0a = sB0 + (wv*64)*8;
    bf16* lb0b = sB0 + (256 + wv*64)*8;
    bf16* lb1a = sB1 + (wv*64)*8;
    bf16* lb1b = sB1 + (256 + wv*64)*8;

    f32x4 accP[4][4], accG[4][4];
    f32x4 zero = {0.f, 0.f, 0.f, 0.f};
#pragma unroll
    for (int mi = 0; mi < 4; ++mi)
#pragma unroll
        for (int ni = 0; ni < 4; ++ni) { accP[mi][ni] = zero; accG[mi][ni] = zero; }

    // --- K-loop: 4 x BK32, cp16-stage weight chunks (L2-resident) ---
    for (int ks = 0; ks < 4; ++ks) {
        __syncthreads();
        cp16(lb0a, Bp + nr0*128 + ks*32 + kc0);
        cp16(lb0b, Bp + nr1*128 + ks*32 + kc1);
        if (branch < 2) {
            cp16(lb1a, Bg + nr0*128 + ks*32 + kc0);
            cp16(lb1b, Bg + nr1*128 + ks*32 + kc1);
        }
        __syncthreads();

        bf16x8 af[4], bp_[4], bg_[4];
#pragma unroll
        for (int i = 0; i < 4; ++i) {
            af[i]  = *(const bf16x8*)(sXh + (m0 + i*16 + l16)*136 + ks*32 + quad*8);
            bp_[i] = *(const bf16x8*)(sB0 + (n0 + i*16 + l16)*32 + quad*8);
        }
        if (branch < 2) {
#pragma unroll
            for (int i = 0; i < 4; ++i)
                bg_[i] = *(const bf16x8*)(sB1 + (n0 + i*16 + l16)*32 + quad*8);
        }
#pragma unroll
        for (int mi = 0; mi < 4; ++mi)
#pragma unroll
            for (int ni = 0; ni < 4; ++ni) {
                accP[mi][ni] = __builtin_amdgcn_mfma_f32_16x16x32_bf16(
                                   af[mi], bp_[ni], accP[mi][ni], 0, 0, 0);
                if (branch < 2)
                    accG[mi][ni] = __builtin_amdgcn_mfma_f32_16x16x32_bf16(
                                       af[mi], bg_[ni], accG[mi][ni], 0, 0, 0);
            }
    }

    // --- Epilogue: combine, transpose-stage in LDS (reuse sXh), store ---
    __syncthreads();
    bf16* sT = sXh;                // 128*132 <= 128*136
    if (branch < 2) {
        bf16* dst = (branch == 0) ? leftT : rightT;
#pragma unroll
        for (int ni = 0; ni < 4; ++ni) {
            int c = n0 + ni*16 + l16;
            float bp = bpb[c];
            float bg = bgb[c];
#pragma unroll
            for (int mi = 0; mi < 4; ++mi)
#pragma unroll
                for (int r = 0; r < 4; ++r) {
                    int m = m0 + mi*16 + quad*4 + r;
                    float val = sMask[m] * (accP[mi][ni][r] + bp)
                                         * sigmoidf_(accG[mi][ni][r] + bg);
                    sT[c*132 + m] = (bf16)val;
                }
        }
        __syncthreads();
#pragma unroll
        for (int i = 0; i < 16; ++i) {      // 128 c x 32 chunks, coalesced
            int chunk = tid + i*256;
            int c = chunk >> 5, u = chunk & 31;
            *(bf16x4*)(dst + (size_t)c*NNF + p0 + u*4) =
                *(const bf16x4*)(sT + c*132 + u*4);
        }
    } else {
#pragma unroll
        for (int ni = 0; ni < 4; ++ni) {
            int c = n0 + ni*16 + l16;
            float bg = bpb[c];
#pragma unroll
            for (int mi = 0; mi < 4; ++mi)
#pragma unroll
                for (int r = 0; r < 4; ++r) {
                    int m = m0 + mi*16 + quad*4 + r;
                    sT[m*132 + c] = (bf16)sigmoidf_(accP[mi][ni][r] + bg);
                }
        }
        __syncthreads();
#pragma unroll
        for (int i = 0; i < 16; ++i) {
            int chunk = tid + i*256;
            int m = chunk >> 5, c4 = chunk & 31;
            *(bf16x4*)(gate + (p0 + m)*CZ + c4*4) =
                *(const bf16x4*)(sT + m*132 + c4*4);
        }
    }
}

// ---------------------------------------------------------------------------
// Kernel 2: per-channel GEMM  Mid[c][i][j] = sum_k L[c][i][k] * R[c][j][k]
// m97-style: 128x128 tile, BK=32, global_load_lds width 16. Grid (6,6,128).
// ---------------------------------------------------------------------------
__global__ __launch_bounds__(256, 2)
void k2_einsum(const bf16* __restrict__ Lt, const bf16* __restrict__ Rt,
               bf16* __restrict__ Mid)
{
    __shared__ bf16 sA[128*32];
    __shared__ bf16 sB[128*32];

    const int tid = threadIdx.x;
    const int bj = blockIdx.x, bi = blockIdx.y, c = blockIdx.z;
    const size_t cb = (size_t)c * NNF;
    const bf16* Ab = Lt + cb + (size_t)bi * 128 * NR;
    const bf16* Bb = Rt + cb + (size_t)bj * 128 * NR;

    const int wv = tid >> 6, lane = tid & 63, l16 = lane & 15, quad = lane >> 4;
    const int m0 = (wv >> 1) * 64, n0 = (wv & 1) * 64;

    const int q0 = tid, q1 = tid + 256;
    const int ra0 = q0 >> 2, kc0 = (q0 & 3) * 8;
    const int ra1 = q1 >> 2, kc1 = (q1 & 3) * 8;
    bf16* lbA0 = sA + (size_t)(wv*64) * 8;
    bf16* lbA1 = sA + (size_t)(256 + wv*64) * 8;
    bf16* lbB0 = sB + (size_t)(wv*64) * 8;
    bf16* lbB1 = sB + (size_t)(256 + wv*64) * 8;

    f32x4 acc[4][4];
    f32x4 zero = {0.f, 0.f, 0.f, 0.f};
#pragma unroll
    for (int mi = 0; mi < 4; ++mi)
#pragma unroll
        for (int ni = 0; ni < 4; ++ni) acc[mi][ni] = zero;

    for (int ko = 0; ko < NR; ko += 32) {
        __syncthreads();
        cp16(lbA0, Ab + (size_t)ra0*NR + ko + kc0);
        cp16(lbA1, Ab + (size_t)ra1*NR + ko + kc1);
        cp16(lbB0, Bb + (size_t)ra0*NR + ko + kc0);
        cp16(lbB1, Bb + (size_t)ra1*NR + ko + kc1);
        __syncthreads();

        bf16x8 af[4], bfr[4];
#pragma unroll
        for (int i = 0; i < 4; ++i) {
            af[i]  = *(const bf16x8*)(sA + (m0 + i*16 + l16)*32 + quad*8);
            bfr[i] = *(const bf16x8*)(sB + (n0 + i*16 + l16)*32 + quad*8);
        }
#pragma unroll
        for (int mi = 0; mi < 4; ++mi)
#pragma unroll
            for (int ni = 0; ni < 4; ++ni)
                acc[mi][ni] = __builtin_amdgcn_mfma_f32_16x16x32_bf16(
                                  af[mi], bfr[ni], acc[mi][ni], 0, 0, 0);
    }

    bf16* Ob = Mid + cb + (size_t)(bi*128) * NR + bj*128;
#pragma unroll
    for (int mi = 0; mi < 4; ++mi)
#pragma unroll
        for (int ni = 0; ni < 4; ++ni) {
            int colv = n0 + ni*16 + l16;
#pragma unroll
            for (int r = 0; r < 4; ++r) {
                int row = m0 + mi*16 + quad*4 + r;
                Ob[(size_t)row*NR + colv] = (bf16)acc[mi][ni][r];
            }
        }
}

// ---------------------------------------------------------------------------
// Kernel 3: transpose [C][NN] -> LN over c -> @W_out + b_out -> * gate -> out
// ---------------------------------------------------------------------------
__global__ __launch_bounds__(256, 2)
void k3_ln_out(const bf16* __restrict__ Mid, const bf16* __restrict__ gate,
               const float* __restrict__ lnw, const float* __restrict__ lnb,
               const float* __restrict__ Wout, const float* __restrict__ bout,
               float* __restrict__ out)
{
    __shared__ bf16 sT[128*68];     // [c][pos]
    __shared__ bf16 sXh[64*136];    // [pos][c]
    __shared__ bf16 sWt[128*136];
    __shared__ float sMu[64], sRs[64];

    const int tid = threadIdx.x;
    const size_t p0 = (size_t)blockIdx.x * 64;

#pragma unroll
    for (int i = 0; i < 8; ++i) {
        int chunk = tid + i*256;
        int c = chunk >> 4, u = chunk & 15;
        *(bf16x4*)(sT + c*68 + u*4) =
            *(const bf16x4*)(Mid + (size_t)c*NNF + p0 + u*4);
    }
#pragma unroll
    for (int i = 0; i < 16; ++i) {
        int chunk = tid + i*256;
        int kk = chunk >> 5;
        int nb = (chunk & 31) * 4;
        float4 w = *(const float4*)(Wout + kk*CZ + nb);
        sWt[(nb+0)*136 + kk] = (bf16)w.x;
        sWt[(nb+1)*136 + kk] = (bf16)w.y;
        sWt[(nb+2)*136 + kk] = (bf16)w.z;
        sWt[(nb+3)*136 + kk] = (bf16)w.w;
    }
    __syncthreads();

    {
        int pos = tid >> 2, part = tid & 3;
        float s = 0.f, q = 0.f;
#pragma unroll
        for (int j = 0; j < 32; ++j) {
            float x = (float)sT[(part*32 + j)*68 + pos];
            s += x; q += x*x;
        }
        s += __shfl_xor(s, 1); q += __shfl_xor(q, 1);
        s += __shfl_xor(s, 2); q += __shfl_xor(q, 2);
        if (part == 0) {
            float mu  = s * (1.f/CZ);
            float var = q * (1.f/CZ) - mu*mu;
            sMu[pos] = mu;
            sRs[pos] = rsqrtf(var + 1e-5f);
        }
    }
    __syncthreads();

#pragma unroll
    for (int i2 = 0; i2 < 8; ++i2) {
        int id = tid + i2*256;
        int pos = id & 63, c4 = id >> 6;
        float mu = sMu[pos], rs = sRs[pos];
        float4 w = *(const float4*)(lnw + c4*4);
        float4 b = *(const float4*)(lnb + c4*4);
        bf16x4 o;
        o[0] = (bf16)(((float)sT[(c4*4+0)*68 + pos] - mu)*rs*w.x + b.x);
        o[1] = (bf16)(((float)sT[(c4*4+1)*68 + pos] - mu)*rs*w.y + b.y);
        o[2] = (bf16)(((float)sT[(c4*4+2)*68 + pos] - mu)*rs*w.z + b.z);
        o[3] = (bf16)(((float)sT[(c4*4+3)*68 + pos] - mu)*rs*w.w + b.w);
        *(bf16x4*)(sXh + pos*136 + c4*4) = o;
    }
    __syncthreads();

    const int wv = tid >> 6, lane = tid & 63, l16 = lane & 15, quad = lane >> 4;
    f32x4 acc[8];
    f32x4 zero = {0.f, 0.f, 0.f, 0.f};
#pragma unroll
    for (int t = 0; t < 8; ++t) acc[t] = zero;
#pragma unroll
    for (int ks = 0; ks < 4; ++ks) {
        bf16x8 af = *(const bf16x8*)(sXh + (wv*16 + l16)*136 + ks*32 + quad*8);
#pragma unroll
        for (int t = 0; t < 8; ++t) {
            bf16x8 bfr = *(const bf16x8*)(sWt + (t*16 + l16)*136 + ks*32 + quad*8);
            acc[t] = __builtin_amdgcn_mfma_f32_16x16x32_bf16(af, bfr, acc[t], 0, 0, 0);
        }
    }
#pragma unroll
    for (int t = 0; t < 8; ++t) {
        int c = t*16 + l16;
        float bo = bout[c];
#pragma unroll
        for (int r = 0; r < 4; ++r) {
            int m = wv*16 + quad*4 + r;
            size_t p = p0 + m;
            float g = (float)gate[p*CZ + c];
            out[p*CZ + c] = (acc[t][r] + bo) * g;
        }
    }
}

// ---------------------------------------------------------------------------
extern "C" void kernel_launch(void* const* d_in, const int* in_sizes, int n_in,
                              void* d_out, int out_size, void* d_ws, size_t ws_size,
                              hipStream_t stream)
{
    const float* act     = (const float*)d_in[0];
    const float* mask    = (const float*)d_in[1];
    const float* ln_in_w = (const float*)d_in[2];
    const float* ln_in_b = (const float*)d_in[3];
    const float* W_lp    = (const float*)d_in[4];
    const float* b_lp    = (const float*)d_in[5];
    const float* W_rp    = (const float*)d_in[6];
    const float* b_rp    = (const float*)d_in[7];
    const float* W_lg    = (const float*)d_in[8];
    const float* b_lg    = (const float*)d_in[9];
    const float* W_rg    = (const float*)d_in[10];
    const float* b_rg    = (const float*)d_in[11];
    const float* ln_c_w  = (const float*)d_in[12];
    const float* ln_c_b  = (const float*)d_in[13];
    const float* W_out   = (const float*)d_in[14];
    const float* b_out   = (const float*)d_in[15];
    const float* W_g     = (const float*)d_in[16];
    const float* b_g     = (const float*)d_in[17];

    char* ws = (char*)d_ws;
    const size_t SZ = (size_t)NNF * CZ * sizeof(bf16);   // 150,994,944 B each
    bf16* leftT  = (bf16*)(ws);
    bf16* rightT = (bf16*)(ws + SZ);
    bf16* gatev  = (bf16*)(ws + 2*SZ);
    bf16* Mid    = (bf16*)(ws + 3*SZ);
    bf16* Wt     = (bf16*)(ws + 3*SZ);   // aliases Mid: Wt dead before k2 writes
    (void)ws_size; (void)in_sizes; (void)n_in; (void)out_size;

    k0_wt<<<5, 256, 0, stream>>>(W_lp, W_lg, W_rp, W_rg, W_g, Wt);

    k1_proj<<<dim3(3, NNF/128), 256, 0, stream>>>(act, mask, ln_in_w, ln_in_b,
        Wt, b_lp, b_lg, b_rp, b_rg, b_g, leftT, rightT, gatev);

    k2_einsum<<<dim3(6, 6, 128), 256, 0, stream>>>(leftT, rightT, Mid);

    k3_ln_out<<<NNF/64, 256, 0, stream>>>(Mid, gatev, ln_c_w, ln_c_b,
        W_out, b_out, (float*)d_out);
}